// Round 15
// baseline (122.495 us; speedup 1.0000x reference)
//
#include <hip/hip_runtime.h>

#define D 128
#define PSHIFT 6
#define PSIZE 64             // dsts per partition
#define EDGES_PER_BLK 4096   // bin kernels: 512 thr x 8 edges
#define CAP 2048             // max records per partition (mean 1280, +21 sigma)
#define MAXPART 1024
#define NCHUNK 4             // dim chunks: 32 dims = 64B/node, 3.2MB/chunk < 4MB L2

typedef __attribute__((ext_vector_type(8))) short bf16x8;
typedef __attribute__((ext_vector_type(4))) float f32x4;

__device__ __forceinline__ unsigned short f2bf(float f) {
  unsigned int u = __float_as_uint(f);
  u = (u + 0x7fffu + ((u >> 16) & 1)) >> 16;
  return (unsigned short)u;
}

// ---------------------------------------------------------------------------
// Fused Pass 0+A: blocks [0, cvtBlocks) convert h f32 -> h16 in CHUNK-MAJOR
// layout h16c[c][n][32]; remaining blocks LDS-histogram edges into 1024
// partition bins + one global atomic per nonzero bin.
// ---------------------------------------------------------------------------
__global__ __launch_bounds__(512) void cvt_hist_kernel(
    const float* __restrict__ h, unsigned short* __restrict__ h16, int total4,
    const int* __restrict__ edst, int* __restrict__ g_hist, int E,
    int cvtBlocks, int N) {
  if ((int)blockIdx.x < cvtBlocks) {
    int i = blockIdx.x * 512 + threadIdx.x;
    if (i >= total4) return;
    float4 v = ((const float4*)h)[i];
    ushort4 o;
    o.x = f2bf(v.x); o.y = f2bf(v.y); o.z = f2bf(v.z); o.w = f2bf(v.w);
    int f = i * 4;
    int n = f >> 7;
    int d = f & 127;
    int c = d >> 5;
    int wi = d & 31;
    ((ushort4*)h16)[(size_t)c * N * 8 + n * 8 + (wi >> 2)] = o;
    return;
  }
  __shared__ int cnt[MAXPART];
  int t = threadIdx.x;
  cnt[t] = 0; cnt[t + 512] = 0;
  __syncthreads();
  int eb = (blockIdx.x - cvtBlocks) * EDGES_PER_BLK;
#pragma unroll
  for (int q = 0; q < 8; ++q) {
    int e = eb + q * 512 + t;
    if (e < E) atomicAdd(&cnt[edst[e] >> PSHIFT], 1);
  }
  __syncthreads();
  int c = cnt[t];
  if (c > 0) atomicAdd(&g_hist[t], c);
  c = cnt[t + 512];
  if (c > 0) atomicAdd(&g_hist[t + 512], c);
}

// ---------------------------------------------------------------------------
// Pass B: single-block pair-scan of 1024 partition counts -> part_off
// (exclusive, +end sentinel) and g_cursor (running allocator).
// ---------------------------------------------------------------------------
__global__ __launch_bounds__(512) void part_scan_kernel(
    const int* __restrict__ g_hist, int* __restrict__ part_off,
    int* __restrict__ g_cursor, int E, int npart) {
  __shared__ int ts[512];
  int t = threadIdx.x;
  int i0 = 2 * t, i1 = 2 * t + 1;
  int v0 = (i0 < npart) ? g_hist[i0] : 0;
  int v1 = (i1 < npart) ? g_hist[i1] : 0;
  ts[t] = v0 + v1;
  __syncthreads();
  for (int off = 1; off < 512; off <<= 1) {
    int x = (t >= off) ? ts[t - off] : 0;
    __syncthreads();
    ts[t] += x;
    __syncthreads();
  }
  int excl = ts[t] - (v0 + v1);
  if (i0 < npart) { part_off[i0] = excl; g_cursor[i0] = excl; }
  if (i1 < npart) { part_off[i1] = excl + v0; g_cursor[i1] = excl + v0; }
  if (t == 0) part_off[npart] = E;
}

// ---------------------------------------------------------------------------
// Pass C: LDS-binned scatter (unchanged).  Record: {src | (dst&63)<<16, coeff}.
// ---------------------------------------------------------------------------
__global__ __launch_bounds__(512) void bin_scatter_kernel(
    const float* __restrict__ alpha, const float* __restrict__ ew,
    const int* __restrict__ node_id, const int* __restrict__ esrc,
    const int* __restrict__ edst, int* __restrict__ g_cursor,
    int2* __restrict__ recs, int E, int gene_num) {
  __shared__ int2 lrec[EDGES_PER_BLK];            // 32 KB
  __shared__ unsigned short lbin[EDGES_PER_BLK];  // 8 KB
  __shared__ int cnt[MAXPART], offl[MAXPART], gbase[MAXPART];  // 12 KB
  __shared__ int ts[512];

  int t = threadIdx.x;
  cnt[t] = 0; cnt[t + 512] = 0;
  __syncthreads();

  int eb = blockIdx.x * EDGES_PER_BLK;
  int rx[8]; float rc[8]; int rb[8]; int rk[8];
#pragma unroll
  for (int q = 0; q < 8; ++q) {
    int e = eb + q * 512 + t;
    rk[q] = -1;
    if (e < E) {
      int src = esrc[e];
      int dst = edst[e];
      int sid = node_id[src];
      int did = node_id[dst];
      int idx;
      if (sid >= 0) idx = (did >= 0) ? gene_num : sid;
      else          idx = (did >= 0) ? did : (gene_num + 1);
      rc[q] = alpha[idx] * ew[e];
      rx[q] = src | ((dst & (PSIZE - 1)) << 16);
      int b = dst >> PSHIFT;
      rb[q] = b;
      rk[q] = atomicAdd(&cnt[b], 1);
    }
  }
  __syncthreads();

  // pair-scan of 1024 bins -> offl exclusive
  int c0 = cnt[2 * t], c1 = cnt[2 * t + 1];
  ts[t] = c0 + c1;
  __syncthreads();
  for (int off = 1; off < 512; off <<= 1) {
    int x = (t >= off) ? ts[t - off] : 0;
    __syncthreads();
    ts[t] += x;
    __syncthreads();
  }
  int exclp = ts[t] - (c0 + c1);
  offl[2 * t] = exclp;
  offl[2 * t + 1] = exclp + c0;
  __syncthreads();

  // place into LDS (sorted by bin)
#pragma unroll
  for (int q = 0; q < 8; ++q) {
    if (rk[q] >= 0) {
      int ls = offl[rb[q]] + rk[q];
      lrec[ls] = make_int2(rx[q], __float_as_int(rc[q]));
      lbin[ls] = (unsigned short)rb[q];
    }
  }
  __syncthreads();

  // reserve global runs (one atomic per nonzero bin)
  {
    int c = cnt[t];
    if (c > 0) gbase[t] = atomicAdd(&g_cursor[t], c);
    c = cnt[t + 512];
    if (c > 0) gbase[t + 512] = atomicAdd(&g_cursor[t + 512], c);
  }
  __syncthreads();

  // coalesced run write-out
  int tot = E - eb;
  if (tot > EDGES_PER_BLK) tot = EDGES_PER_BLK;
  for (int s = t; s < tot; s += 512) {
    int b = lbin[s];
    recs[gbase[b] + (s - offl[b])] = lrec[s];
  }
}

// ---------------------------------------------------------------------------
// Pass C2: per-partition sort-once.  Stage the partition's records, LDS
// counting-sort by dst&63, write back SORTED in place (coalesced), and emit
// cnt_g / off_g (exact excl) / rk_g (rank->dl, counts descending).
// ---------------------------------------------------------------------------
__global__ __launch_bounds__(512) void sort_kernel(
    int2* __restrict__ recs, const int* __restrict__ part_off,
    int* __restrict__ cnt_g, int* __restrict__ off_g,
    int* __restrict__ rk_g) {
  __shared__ int2 lrec[CAP];              // 16 KB
  __shared__ int cnt[PSIZE], offl[PSIZE];

  int t = threadIdx.x;
  int p = blockIdx.x;
  if (t < PSIZE) cnt[t] = 0;
  __syncthreads();

  int start = part_off[p];
  int R = part_off[p + 1] - start;
  if (R > CAP) R = CAP;

  int2 rq[4]; int dlq[4]; int rkq[4];
#pragma unroll
  for (int q = 0; q < 4; ++q) {
    int s = q * 512 + t;
    rkq[q] = -1;
    if (s < R) {
      int2 r = recs[start + s];
      rq[q] = r;
      int dl = (r.x >> 16) & (PSIZE - 1);
      dlq[q] = dl;
      rkq[q] = atomicAdd(&cnt[dl], 1);
    }
  }
  __syncthreads();

  // exclusive scan of 64 bins
  if (t < PSIZE) offl[t] = cnt[t];
  __syncthreads();
  for (int off = 1; off < PSIZE; off <<= 1) {
    int x = 0;
    if (t < PSIZE && t >= off) x = offl[t - off];
    __syncthreads();
    if (t < PSIZE) offl[t] += x;
    __syncthreads();
  }
  if (t < PSIZE) offl[t] -= cnt[t];
  __syncthreads();

#pragma unroll
  for (int q = 0; q < 4; ++q)
    if (rkq[q] >= 0) lrec[offl[dlq[q]] + rkq[q]] = rq[q];
  __syncthreads();

  for (int s = t; s < R; s += 512) recs[start + s] = lrec[s];
  if (t < PSIZE) {
    cnt_g[p * PSIZE + t] = cnt[t];
    off_g[p * PSIZE + t] = offl[t];
    // rank of dst t by count descending (ties by index): O(64) per thread
    int my = cnt[t];
    int r = 0;
    for (int j = 0; j < PSIZE; ++j) {
      int cj = cnt[j];
      r += (cj > my) || (cj == my && j < t);
    }
    rk_g[p * PSIZE + r] = t;   // rank -> dl
  }
}

// ---------------------------------------------------------------------------
// Pass D: per-(partition, dim-chunk) accumulate, LDS-FREE.  bid = p*4 + c;
// round-robin block->XCD keeps chunk c on XCDs with xcd&3==c -> 3.2MB h16
// slice L2-resident.  Records are pre-sorted: each 16-lane group walks its
// dst's CONTIGUOUS global run directly (uniform-per-group dwordx2 reads,
// 1 line / 8 records, L1-hot).  Degree-balanced: quad Q = ranks 4Q..4Q+3,
// wave w pairs quads {w, 15-w}.  8-deep main batches + guarded 4-wide tail
// (addr clamped to row 0, coeff 0).  No barriers, no staging.
// ---------------------------------------------------------------------------
__global__ __launch_bounds__(512) void part_acc_kernel(
    const unsigned short* __restrict__ h16, const int2* __restrict__ recs,
    const int* __restrict__ part_off, const int* __restrict__ cnt_g,
    const int* __restrict__ off_g, const int* __restrict__ rk_g,
    float* __restrict__ neigh, int N) {
  int t = threadIdx.x;
  int p = blockIdx.x >> 2;
  int chunk = blockIdx.x & 3;
  int start = part_off[p];

  int w = t >> 6;
  int l = t & 63;
  int esub = l >> 4;        // 0..3: which dst in the quad
  int dpair = l & 15;       // dim pair within chunk (16 uints = 32 dims)
  const unsigned int* hpc =
      ((const unsigned int*)h16) + (size_t)chunk * N * 16 + dpair;

#pragma unroll
  for (int h2 = 0; h2 < 2; ++h2) {
    int Q = (h2 == 0) ? w : (15 - w);       // pair big with small
    int myDl = rk_g[p * PSIZE + Q * 4 + esub];
    int myCnt = cnt_g[p * PSIZE + myDl];
    int myBase = start + off_g[p * PSIZE + myDl];
    float ax = 0.f, ay = 0.f;
    int k = 0;
    for (; k + 8 <= myCnt; k += 8) {        // 8 loads in flight per group
      unsigned int v[8]; float c[8];
#pragma unroll
      for (int q = 0; q < 8; ++q) {
        int2 r = recs[myBase + k + q];
        c[q] = __int_as_float(r.y);
        v[q] = hpc[(size_t)(r.x & 0xffff) * 16];
      }
#pragma unroll
      for (int q = 0; q < 8; ++q) {
        ax += c[q] * __uint_as_float(v[q] << 16);
        ay += c[q] * __uint_as_float(v[q] & 0xffff0000u);
      }
    }
    for (; k < myCnt; k += 4) {             // guarded tail (<=2 iterations)
      unsigned int v[4]; float c[4];
#pragma unroll
      for (int q = 0; q < 4; ++q) {
        int sl = k + q;
        int2 r = recs[myBase + sl];         // slack records appended to recs
        bool ok = sl < myCnt;
        c[q] = ok ? __int_as_float(r.y) : 0.f;
        unsigned int a = ok ? (unsigned int)(r.x & 0xffff) : 0u;
        v[q] = hpc[(size_t)a * 16];
      }
#pragma unroll
      for (int q = 0; q < 4; ++q) {
        ax += c[q] * __uint_as_float(v[q] << 16);
        ay += c[q] * __uint_as_float(v[q] & 0xffff0000u);
      }
    }
    int dst = p * PSIZE + myDl;
    if (dst < N) {
      float inv = 1.0f / (float)(myCnt > 0 ? myCnt : 1);
      ((float2*)neigh)[(size_t)dst * 64 + chunk * 16 + dpair] =
          make_float2(ax * inv, ay * inv);
    }
  }
}

// ---------------------------------------------------------------------------
// MLP (MFMA): io = relu(io @ W.T + b), in place on d_out.  (unchanged)
// ---------------------------------------------------------------------------
__global__ __launch_bounds__(256) void mlp_mfma_kernel(
    const float* __restrict__ W, const float* __restrict__ bias,
    float* __restrict__ io, int N) {
  __shared__ __align__(16) unsigned short Wl[128 * 128];  // 32 KB bf16

  int t = threadIdx.x;
#pragma unroll
  for (int i = 0; i < 8; ++i) {
    int chunk = t + 256 * i;
    int row = chunk >> 4;
    int cb = chunk & 15;
    const float* gp = W + (size_t)row * 128 + cb * 8;
    float4 a = *(const float4*)gp;
    float4 b = *(const float4*)(gp + 4);
    bf16x8 v;
    v[0] = (short)f2bf(a.x); v[1] = (short)f2bf(a.y);
    v[2] = (short)f2bf(a.z); v[3] = (short)f2bf(a.w);
    v[4] = (short)f2bf(b.x); v[5] = (short)f2bf(b.y);
    v[6] = (short)f2bf(b.z); v[7] = (short)f2bf(b.w);
    *(bf16x8*)((char*)Wl + row * 256 + ((cb ^ (row & 7)) << 4)) = v;
  }
  __syncthreads();

  int l = t & 63;
  int w = t >> 6;
  int kg = l >> 4;
  int m_base = blockIdx.x * 64 + w * 16;
  int arow = m_base + (l & 15);
  if (arow >= N) arow = N - 1;

  bf16x8 af[4];
  const float* ap = io + (size_t)arow * 128 + kg * 8;
#pragma unroll
  for (int kk = 0; kk < 4; ++kk) {
    float4 a = *(const float4*)(ap + kk * 32);
    float4 b = *(const float4*)(ap + kk * 32 + 4);
    bf16x8 v;
    v[0] = (short)f2bf(a.x); v[1] = (short)f2bf(a.y);
    v[2] = (short)f2bf(a.z); v[3] = (short)f2bf(a.w);
    v[4] = (short)f2bf(b.x); v[5] = (short)f2bf(b.y);
    v[6] = (short)f2bf(b.z); v[7] = (short)f2bf(b.w);
    af[kk] = v;
  }

#pragma unroll
  for (int c = 0; c < 8; ++c) {
    f32x4 acc = {0.f, 0.f, 0.f, 0.f};
    int row_w = c * 16 + (l & 15);
    int rs = row_w & 7;
#pragma unroll
    for (int kk = 0; kk < 4; ++kk) {
      int cb = kk * 4 + kg;
      bf16x8 bf = *(bf16x8*)((char*)Wl + row_w * 256 + ((cb ^ rs) << 4));
      acc = __builtin_amdgcn_mfma_f32_16x16x32_bf16(af[kk], bf, acc, 0, 0, 0);
    }
    int j = c * 16 + (l & 15);
    float bj = bias[j];
#pragma unroll
    for (int r = 0; r < 4; ++r) {
      int m = m_base + kg * 4 + r;
      if (m < N) io[(size_t)m * 128 + j] = fmaxf(acc[r] + bj, 0.0f);
    }
  }
}

extern "C" void kernel_launch(void* const* d_in, const int* in_sizes, int n_in,
                              void* d_out, int out_size, void* d_ws, size_t ws_size,
                              hipStream_t stream) {
  const float* h     = (const float*)d_in[0];
  const float* alpha = (const float*)d_in[1];
  const float* ew    = (const float*)d_in[2];
  const float* W     = (const float*)d_in[3];
  const float* bias  = (const float*)d_in[4];
  const int* node_id = (const int*)d_in[5];
  const int* esrc    = (const int*)d_in[6];
  const int* edst    = (const int*)d_in[7];
  float* out = (float*)d_out;

  int E = in_sizes[2];
  int N = in_sizes[5];
  int gene_num = in_sizes[1] - 2;
  int npart = (N + PSIZE - 1) / PSIZE;          // 782 (must be <= 1024)
  int eblocks = (E + EDGES_PER_BLK - 1) / EDGES_PER_BLK;  // 245
  int total4 = N * D / 4;
  int cvtBlocks = (total4 + 511) / 512;         // 3125

  // workspace layout
  int* g_hist   = (int*)d_ws;                   // 1024
  int* part_off = g_hist + MAXPART;             // npart+1 (<=1025)
  int* g_cursor = part_off + MAXPART + 1;       // 1024
  int* cnt_g    = g_cursor + MAXPART;           // npart*64 <= 65536
  int* off_g    = cnt_g + MAXPART * PSIZE;      // npart*64 <= 65536
  int* rk_g     = off_g + MAXPART * PSIZE;      // npart*64 <= 65536
  size_t h16_off = ((size_t)(3 * MAXPART + 1 + 3 * MAXPART * PSIZE) * sizeof(int)
                    + 15) & ~(size_t)15;
  unsigned short* h16 = (unsigned short*)((char*)d_ws + h16_off);  // chunk-major
  size_t rec_off = (h16_off + (size_t)N * D * sizeof(unsigned short) + 15) & ~(size_t)15;
  int2* recs = (int2*)((char*)d_ws + rec_off);  // (E + 8) * 8B (tail slack)
  size_t need = rec_off + (size_t)(E + 8) * sizeof(int2);
  if (ws_size < need) return;

  hipMemsetAsync(g_hist, 0, MAXPART * sizeof(int), stream);

  cvt_hist_kernel<<<cvtBlocks + eblocks, 512, 0, stream>>>(
      h, h16, total4, edst, g_hist, E, cvtBlocks, N);
  part_scan_kernel<<<1, 512, 0, stream>>>(g_hist, part_off, g_cursor, E, npart);
  bin_scatter_kernel<<<eblocks, 512, 0, stream>>>(alpha, ew, node_id, esrc,
                                                  edst, g_cursor, recs, E,
                                                  gene_num);
  sort_kernel<<<npart, 512, 0, stream>>>(recs, part_off, cnt_g, off_g, rk_g);
  part_acc_kernel<<<npart * NCHUNK, 512, 0, stream>>>(h16, recs, part_off,
                                                      cnt_g, off_g, rk_g,
                                                      out, N);
  {
    int blocks = (N + 63) / 64;
    mlp_mfma_kernel<<<blocks, 256, 0, stream>>>(W, bias, out, N);
  }
}

// Round 16
// 109.148 us; speedup vs baseline: 1.1223x; 1.1223x over previous
//
#include <hip/hip_runtime.h>

#define D 128
#define PSHIFT 6
#define PSIZE 64             // dsts per partition
#define EDGES_PER_BLK 4096   // bin kernels: 512 thr x 8 edges
#define CAP 2048             // max records per partition (mean 1280, +21 sigma)
#define PSTRIDE 2240         // padded slots per partition: CAP + 64*3
#define MAXPART 1024
#define NCHUNK 4             // dim chunks: 32 dims = 64B/node, 3.2MB/chunk < 4MB L2

typedef __attribute__((ext_vector_type(8))) short bf16x8;
typedef __attribute__((ext_vector_type(4))) float f32x4;

__device__ __forceinline__ unsigned short f2bf(float f) {
  unsigned int u = __float_as_uint(f);
  u = (u + 0x7fffu + ((u >> 16) & 1)) >> 16;
  return (unsigned short)u;
}

// ---------------------------------------------------------------------------
// Fused Pass 0+A: blocks [0, cvtBlocks) convert h f32 -> h16 in CHUNK-MAJOR
// layout h16c[c][n][32]; remaining blocks LDS-histogram edges into 1024
// partition bins + one global atomic per nonzero bin.
// ---------------------------------------------------------------------------
__global__ __launch_bounds__(512) void cvt_hist_kernel(
    const float* __restrict__ h, unsigned short* __restrict__ h16, int total4,
    const int* __restrict__ edst, int* __restrict__ g_hist, int E,
    int cvtBlocks, int N) {
  if ((int)blockIdx.x < cvtBlocks) {
    int i = blockIdx.x * 512 + threadIdx.x;
    if (i >= total4) return;
    float4 v = ((const float4*)h)[i];
    ushort4 o;
    o.x = f2bf(v.x); o.y = f2bf(v.y); o.z = f2bf(v.z); o.w = f2bf(v.w);
    int f = i * 4;
    int n = f >> 7;
    int d = f & 127;
    int c = d >> 5;
    int wi = d & 31;
    ((ushort4*)h16)[(size_t)c * N * 8 + n * 8 + (wi >> 2)] = o;
    return;
  }
  __shared__ int cnt[MAXPART];
  int t = threadIdx.x;
  cnt[t] = 0; cnt[t + 512] = 0;
  __syncthreads();
  int eb = (blockIdx.x - cvtBlocks) * EDGES_PER_BLK;
#pragma unroll
  for (int q = 0; q < 8; ++q) {
    int e = eb + q * 512 + t;
    if (e < E) atomicAdd(&cnt[edst[e] >> PSHIFT], 1);
  }
  __syncthreads();
  int c = cnt[t];
  if (c > 0) atomicAdd(&g_hist[t], c);
  c = cnt[t + 512];
  if (c > 0) atomicAdd(&g_hist[t + 512], c);
}

// ---------------------------------------------------------------------------
// Pass B: single-block pair-scan of 1024 partition counts -> part_off
// (exclusive, +end sentinel) and g_cursor (running allocator).
// ---------------------------------------------------------------------------
__global__ __launch_bounds__(512) void part_scan_kernel(
    const int* __restrict__ g_hist, int* __restrict__ part_off,
    int* __restrict__ g_cursor, int E, int npart) {
  __shared__ int ts[512];
  int t = threadIdx.x;
  int i0 = 2 * t, i1 = 2 * t + 1;
  int v0 = (i0 < npart) ? g_hist[i0] : 0;
  int v1 = (i1 < npart) ? g_hist[i1] : 0;
  ts[t] = v0 + v1;
  __syncthreads();
  for (int off = 1; off < 512; off <<= 1) {
    int x = (t >= off) ? ts[t - off] : 0;
    __syncthreads();
    ts[t] += x;
    __syncthreads();
  }
  int excl = ts[t] - (v0 + v1);
  if (i0 < npart) { part_off[i0] = excl; g_cursor[i0] = excl; }
  if (i1 < npart) { part_off[i1] = excl + v0; g_cursor[i1] = excl + v0; }
  if (t == 0) part_off[npart] = E;
}

// ---------------------------------------------------------------------------
// Pass C: LDS-binned scatter.  Per block: 4096 edges -> coeff (bf16),
// counting-sort into LDS by partition, reserve global runs with ONE atomic
// per bin, write coalesced runs of COMPACT records.
// recs4: {src | coeff_bf16<<16} (4B);  dl8: dst&63 (1B).
// ---------------------------------------------------------------------------
__global__ __launch_bounds__(512) void bin_scatter_kernel(
    const float* __restrict__ alpha, const float* __restrict__ ew,
    const int* __restrict__ node_id, const int* __restrict__ esrc,
    const int* __restrict__ edst, int* __restrict__ g_cursor,
    unsigned int* __restrict__ recs4, unsigned char* __restrict__ dl8,
    int E, int gene_num) {
  __shared__ unsigned int lrec[EDGES_PER_BLK];    // 16 KB
  __shared__ unsigned short lbin[EDGES_PER_BLK];  // 8 KB
  __shared__ unsigned char ldl[EDGES_PER_BLK];    // 4 KB
  __shared__ int cnt[MAXPART], offl[MAXPART], gbase[MAXPART];  // 12 KB
  __shared__ int ts[512];

  int t = threadIdx.x;
  cnt[t] = 0; cnt[t + 512] = 0;
  __syncthreads();

  int eb = blockIdx.x * EDGES_PER_BLK;
  unsigned int rx[8]; int rb[8]; int rk[8]; int rdl[8];
#pragma unroll
  for (int q = 0; q < 8; ++q) {
    int e = eb + q * 512 + t;
    rk[q] = -1;
    if (e < E) {
      int src = esrc[e];
      int dst = edst[e];
      int sid = node_id[src];
      int did = node_id[dst];
      int idx;
      if (sid >= 0) idx = (did >= 0) ? gene_num : sid;
      else          idx = (did >= 0) ? did : (gene_num + 1);
      float coeff = alpha[idx] * ew[e];
      rx[q] = (unsigned int)src | ((unsigned int)f2bf(coeff) << 16);
      rdl[q] = dst & (PSIZE - 1);
      int b = dst >> PSHIFT;
      rb[q] = b;
      rk[q] = atomicAdd(&cnt[b], 1);
    }
  }
  __syncthreads();

  // pair-scan of 1024 bins -> offl exclusive
  int c0 = cnt[2 * t], c1 = cnt[2 * t + 1];
  ts[t] = c0 + c1;
  __syncthreads();
  for (int off = 1; off < 512; off <<= 1) {
    int x = (t >= off) ? ts[t - off] : 0;
    __syncthreads();
    ts[t] += x;
    __syncthreads();
  }
  int exclp = ts[t] - (c0 + c1);
  offl[2 * t] = exclp;
  offl[2 * t + 1] = exclp + c0;
  __syncthreads();

  // place into LDS (sorted by partition bin)
#pragma unroll
  for (int q = 0; q < 8; ++q) {
    if (rk[q] >= 0) {
      int ls = offl[rb[q]] + rk[q];
      lrec[ls] = rx[q];
      lbin[ls] = (unsigned short)rb[q];
      ldl[ls] = (unsigned char)rdl[q];
    }
  }
  __syncthreads();

  // reserve global runs (one atomic per nonzero bin)
  {
    int c = cnt[t];
    if (c > 0) gbase[t] = atomicAdd(&g_cursor[t], c);
    c = cnt[t + 512];
    if (c > 0) gbase[t + 512] = atomicAdd(&g_cursor[t + 512], c);
  }
  __syncthreads();

  // coalesced run write-out
  int tot = E - eb;
  if (tot > EDGES_PER_BLK) tot = EDGES_PER_BLK;
  for (int s = t; s < tot; s += 512) {
    int b = lbin[s];
    int pos = gbase[b] + (s - offl[b]);
    recs4[pos] = lrec[s];
    dl8[pos] = ldl[s];
  }
}

// ---------------------------------------------------------------------------
// Pass C2: per-partition sort-once.  Read the partition's compact records,
// counting-sort by dl into PAD-TO-4 LDS slots (pre-zeroed -> pad slots are
// {src 0, coeff 0}), write the padded image to recs4p[p*PSTRIDE] and emit
// cnt_g / pad_g (padded excl offsets) / rk_g (rank->dl, counts descending).
// ---------------------------------------------------------------------------
__global__ __launch_bounds__(512) void sort_kernel(
    const unsigned int* __restrict__ recs4, const unsigned char* __restrict__ dl8,
    const int* __restrict__ part_off, unsigned int* __restrict__ recs4p,
    int* __restrict__ cnt_g, int* __restrict__ pad_g, int* __restrict__ rk_g) {
  __shared__ unsigned int lrec[PSTRIDE];  // 8.75 KB, padded image
  __shared__ int cnt[PSIZE], padl[PSIZE];

  int t = threadIdx.x;
  int p = blockIdx.x;
  if (t < PSIZE) cnt[t] = 0;
  for (int s = t; s < PSTRIDE; s += 512) lrec[s] = 0u;
  __syncthreads();

  int start = part_off[p];
  int R = part_off[p + 1] - start;
  if (R > CAP) R = CAP;

  unsigned int rq[4]; int dlq[4]; int rkq[4];
#pragma unroll
  for (int q = 0; q < 4; ++q) {
    int s = q * 512 + t;
    rkq[q] = -1;
    if (s < R) {
      rq[q] = recs4[start + s];
      int dl = dl8[start + s];
      dlq[q] = dl;
      rkq[q] = atomicAdd(&cnt[dl], 1);
    }
  }
  __syncthreads();

  // exclusive scan of padded (to 4) bin sizes
  if (t < PSIZE) padl[t] = (cnt[t] + 3) & ~3;
  __syncthreads();
  for (int off = 1; off < PSIZE; off <<= 1) {
    int x = 0;
    if (t < PSIZE && t >= off) x = padl[t - off];
    __syncthreads();
    if (t < PSIZE) padl[t] += x;
    __syncthreads();
  }
  if (t < PSIZE) padl[t] -= (cnt[t] + 3) & ~3;
  __syncthreads();

#pragma unroll
  for (int q = 0; q < 4; ++q)
    if (rkq[q] >= 0) lrec[padl[dlq[q]] + rkq[q]] = rq[q];
  __syncthreads();

  int padTot = padl[PSIZE - 1] + ((cnt[PSIZE - 1] + 3) & ~3);
  for (int s = t; s < padTot; s += 512)
    recs4p[(size_t)p * PSTRIDE + s] = lrec[s];
  if (t < PSIZE) {
    cnt_g[p * PSIZE + t] = cnt[t];
    pad_g[p * PSIZE + t] = padl[t];
    // rank of dst t by count descending (ties by index)
    int my = cnt[t];
    int r = 0;
    for (int j = 0; j < PSIZE; ++j) {
      int cj = cnt[j];
      r += (cj > my) || (cj == my && j < t);
    }
    rk_g[p * PSIZE + r] = t;   // rank -> dl
  }
}

// ---------------------------------------------------------------------------
// Pass D: per-(partition, dim-chunk) accumulate.  bid = p*4 + c; round-robin
// block->XCD keeps chunk c on XCDs with xcd&3==c -> 3.2MB h16 slice
// L2-resident.  Staging: straight contiguous copy of the pre-padded compact
// image (no zero-fill, no placement math, 9KB LDS).  Walk: 8 waves, 4
// independent dsts/quad (16-lane group per dst), degree-balanced (quad Q =
// ranks 4Q..4Q+3; wave w pairs quads {w,15-w}), 8-deep batches + 4-wide
// tail, unguarded (pad slots are real zeros: src 0 -> row 0, coeff 0).
// ---------------------------------------------------------------------------
__global__ __launch_bounds__(512) void part_acc_kernel(
    const unsigned short* __restrict__ h16, const unsigned int* __restrict__ recs4p,
    const int* __restrict__ cnt_g, const int* __restrict__ pad_g,
    const int* __restrict__ rk_g, float* __restrict__ neigh, int N) {
  __shared__ unsigned int lrec[PSTRIDE];  // 8.75 KB

  int t = threadIdx.x;
  int p = blockIdx.x >> 2;
  int chunk = blockIdx.x & 3;

  int padTot = pad_g[p * PSIZE + PSIZE - 1] +
               ((cnt_g[p * PSIZE + PSIZE - 1] + 3) & ~3);
  for (int s = t; s < padTot; s += 512)
    lrec[s] = recs4p[(size_t)p * PSTRIDE + s];
  __syncthreads();

  int w = t >> 6;
  int l = t & 63;
  int esub = l >> 4;        // 0..3: which dst in the quad
  int dpair = l & 15;       // dim pair within chunk (16 uints = 32 dims)
  const unsigned int* hpc =
      ((const unsigned int*)h16) + (size_t)chunk * N * 16 + dpair;

#pragma unroll
  for (int h2 = 0; h2 < 2; ++h2) {
    int Q = (h2 == 0) ? w : (15 - w);       // pair big with small
    int myDl = rk_g[p * PSIZE + Q * 4 + esub];
    int myCnt = cnt_g[p * PSIZE + myDl];
    int myOff = pad_g[p * PSIZE + myDl];
    int myPad = (myCnt + 3) & ~3;
    float ax = 0.f, ay = 0.f;
    int k = 0;
    for (; k + 8 <= myPad; k += 8) {        // 8 loads in flight per group
      unsigned int v[8]; float c[8];
#pragma unroll
      for (int q = 0; q < 8; ++q) {
        unsigned int r = lrec[myOff + k + q];
        c[q] = __uint_as_float(r & 0xffff0000u);
        v[q] = hpc[(size_t)(r & 0xffffu) * 16];
      }
#pragma unroll
      for (int q = 0; q < 8; ++q) {
        ax += c[q] * __uint_as_float(v[q] << 16);
        ay += c[q] * __uint_as_float(v[q] & 0xffff0000u);
      }
    }
    if (k < myPad) {                        // one 4-batch tail (pads are zero)
      unsigned int v[4]; float c[4];
#pragma unroll
      for (int q = 0; q < 4; ++q) {
        unsigned int r = lrec[myOff + k + q];
        c[q] = __uint_as_float(r & 0xffff0000u);
        v[q] = hpc[(size_t)(r & 0xffffu) * 16];
      }
#pragma unroll
      for (int q = 0; q < 4; ++q) {
        ax += c[q] * __uint_as_float(v[q] << 16);
        ay += c[q] * __uint_as_float(v[q] & 0xffff0000u);
      }
    }
    int dst = p * PSIZE + myDl;
    if (dst < N) {
      float inv = 1.0f / (float)(myCnt > 0 ? myCnt : 1);
      ((float2*)neigh)[(size_t)dst * 64 + chunk * 16 + dpair] =
          make_float2(ax * inv, ay * inv);
    }
  }
}

// ---------------------------------------------------------------------------
// MLP (MFMA): io = relu(io @ W.T + b), in place on d_out.  (unchanged)
// ---------------------------------------------------------------------------
__global__ __launch_bounds__(256) void mlp_mfma_kernel(
    const float* __restrict__ W, const float* __restrict__ bias,
    float* __restrict__ io, int N) {
  __shared__ __align__(16) unsigned short Wl[128 * 128];  // 32 KB bf16

  int t = threadIdx.x;
#pragma unroll
  for (int i = 0; i < 8; ++i) {
    int chunk = t + 256 * i;
    int row = chunk >> 4;
    int cb = chunk & 15;
    const float* gp = W + (size_t)row * 128 + cb * 8;
    float4 a = *(const float4*)gp;
    float4 b = *(const float4*)(gp + 4);
    bf16x8 v;
    v[0] = (short)f2bf(a.x); v[1] = (short)f2bf(a.y);
    v[2] = (short)f2bf(a.z); v[3] = (short)f2bf(a.w);
    v[4] = (short)f2bf(b.x); v[5] = (short)f2bf(b.y);
    v[6] = (short)f2bf(b.z); v[7] = (short)f2bf(b.w);
    *(bf16x8*)((char*)Wl + row * 256 + ((cb ^ (row & 7)) << 4)) = v;
  }
  __syncthreads();

  int l = t & 63;
  int w = t >> 6;
  int kg = l >> 4;
  int m_base = blockIdx.x * 64 + w * 16;
  int arow = m_base + (l & 15);
  if (arow >= N) arow = N - 1;

  bf16x8 af[4];
  const float* ap = io + (size_t)arow * 128 + kg * 8;
#pragma unroll
  for (int kk = 0; kk < 4; ++kk) {
    float4 a = *(const float4*)(ap + kk * 32);
    float4 b = *(const float4*)(ap + kk * 32 + 4);
    bf16x8 v;
    v[0] = (short)f2bf(a.x); v[1] = (short)f2bf(a.y);
    v[2] = (short)f2bf(a.z); v[3] = (short)f2bf(a.w);
    v[4] = (short)f2bf(b.x); v[5] = (short)f2bf(b.y);
    v[6] = (short)f2bf(b.z); v[7] = (short)f2bf(b.w);
    af[kk] = v;
  }

#pragma unroll
  for (int c = 0; c < 8; ++c) {
    f32x4 acc = {0.f, 0.f, 0.f, 0.f};
    int row_w = c * 16 + (l & 15);
    int rs = row_w & 7;
#pragma unroll
    for (int kk = 0; kk < 4; ++kk) {
      int cb = kk * 4 + kg;
      bf16x8 bf = *(bf16x8*)((char*)Wl + row_w * 256 + ((cb ^ rs) << 4));
      acc = __builtin_amdgcn_mfma_f32_16x16x32_bf16(af[kk], bf, acc, 0, 0, 0);
    }
    int j = c * 16 + (l & 15);
    float bj = bias[j];
#pragma unroll
    for (int r = 0; r < 4; ++r) {
      int m = m_base + kg * 4 + r;
      if (m < N) io[(size_t)m * 128 + j] = fmaxf(acc[r] + bj, 0.0f);
    }
  }
}

extern "C" void kernel_launch(void* const* d_in, const int* in_sizes, int n_in,
                              void* d_out, int out_size, void* d_ws, size_t ws_size,
                              hipStream_t stream) {
  const float* h     = (const float*)d_in[0];
  const float* alpha = (const float*)d_in[1];
  const float* ew    = (const float*)d_in[2];
  const float* W     = (const float*)d_in[3];
  const float* bias  = (const float*)d_in[4];
  const int* node_id = (const int*)d_in[5];
  const int* esrc    = (const int*)d_in[6];
  const int* edst    = (const int*)d_in[7];
  float* out = (float*)d_out;

  int E = in_sizes[2];
  int N = in_sizes[5];
  int gene_num = in_sizes[1] - 2;
  int npart = (N + PSIZE - 1) / PSIZE;          // 782 (must be <= 1024)
  int eblocks = (E + EDGES_PER_BLK - 1) / EDGES_PER_BLK;  // 245
  int total4 = N * D / 4;
  int cvtBlocks = (total4 + 511) / 512;         // 3125

  // workspace layout
  int* g_hist   = (int*)d_ws;                   // 1024
  int* part_off = g_hist + MAXPART;             // npart+1 (<=1025)
  int* g_cursor = part_off + MAXPART + 1;       // 1024
  int* cnt_g    = g_cursor + MAXPART;           // npart*64 <= 65536
  int* pad_g    = cnt_g + MAXPART * PSIZE;      // npart*64 <= 65536
  int* rk_g     = pad_g + MAXPART * PSIZE;      // npart*64 <= 65536
  size_t h16_off = ((size_t)(3 * MAXPART + 1 + 3 * MAXPART * PSIZE) * sizeof(int)
                    + 15) & ~(size_t)15;
  unsigned short* h16 = (unsigned short*)((char*)d_ws + h16_off);  // chunk-major
  size_t r4_off = (h16_off + (size_t)N * D * sizeof(unsigned short) + 15) & ~(size_t)15;
  unsigned int* recs4 = (unsigned int*)((char*)d_ws + r4_off);     // (E+8)*4B
  size_t dl_off = (r4_off + (size_t)(E + 8) * 4 + 15) & ~(size_t)15;
  unsigned char* dl8 = (unsigned char*)((char*)d_ws + dl_off);     // E+8
  size_t r4p_off = (dl_off + (size_t)(E + 8) + 15) & ~(size_t)15;
  unsigned int* recs4p = (unsigned int*)((char*)d_ws + r4p_off);   // npart*PSTRIDE*4B
  size_t need = r4p_off + (size_t)npart * PSTRIDE * 4;
  if (ws_size < need) return;

  hipMemsetAsync(g_hist, 0, MAXPART * sizeof(int), stream);

  cvt_hist_kernel<<<cvtBlocks + eblocks, 512, 0, stream>>>(
      h, h16, total4, edst, g_hist, E, cvtBlocks, N);
  part_scan_kernel<<<1, 512, 0, stream>>>(g_hist, part_off, g_cursor, E, npart);
  bin_scatter_kernel<<<eblocks, 512, 0, stream>>>(alpha, ew, node_id, esrc,
                                                  edst, g_cursor, recs4, dl8,
                                                  E, gene_num);
  sort_kernel<<<npart, 512, 0, stream>>>(recs4, dl8, part_off, recs4p,
                                         cnt_g, pad_g, rk_g);
  part_acc_kernel<<<npart * NCHUNK, 512, 0, stream>>>(h16, recs4p, cnt_g,
                                                      pad_g, rk_g, out, N);
  {
    int blocks = (N + 63) / 64;
    mlp_mfma_kernel<<<blocks, 256, 0, stream>>>(W, bias, out, N);
  }
}

// Round 17
// 106.443 us; speedup vs baseline: 1.1508x; 1.0254x over previous
//
#include <hip/hip_runtime.h>

#define D 128
#define PSHIFT 6
#define PSIZE 64             // dsts per partition
#define EDGES_PER_BLK 4096   // bin kernels: 512 thr x 8 edges
#define CAP 2048             // max records per partition (mean 1280, +21 sigma)
#define PSTRIDE 2240         // padded slots per partition: CAP + 64*3
#define MAXPART 1024
#define NCHUNK 4             // dim chunks: 32 dims = 64B/node, 3.2MB/chunk < 4MB L2

typedef __attribute__((ext_vector_type(8))) short bf16x8;
typedef __attribute__((ext_vector_type(4))) float f32x4;

__device__ __forceinline__ unsigned short f2bf(float f) {
  unsigned int u = __float_as_uint(f);
  u = (u + 0x7fffu + ((u >> 16) & 1)) >> 16;
  return (unsigned short)u;
}

// ---------------------------------------------------------------------------
// Fused Pass 0+A: blocks [0, cvtBlocks) convert h f32 -> h16 in CHUNK-MAJOR
// layout h16c[c][n][32]; remaining blocks LDS-histogram edges into 1024
// partition bins + one global atomic per nonzero bin.
// ---------------------------------------------------------------------------
__global__ __launch_bounds__(512) void cvt_hist_kernel(
    const float* __restrict__ h, unsigned short* __restrict__ h16, int total4,
    const int* __restrict__ edst, int* __restrict__ g_hist, int E,
    int cvtBlocks, int N) {
  if ((int)blockIdx.x < cvtBlocks) {
    int i = blockIdx.x * 512 + threadIdx.x;
    if (i >= total4) return;
    float4 v = ((const float4*)h)[i];
    ushort4 o;
    o.x = f2bf(v.x); o.y = f2bf(v.y); o.z = f2bf(v.z); o.w = f2bf(v.w);
    int f = i * 4;
    int n = f >> 7;
    int d = f & 127;
    int c = d >> 5;
    int wi = d & 31;
    ((ushort4*)h16)[(size_t)c * N * 8 + n * 8 + (wi >> 2)] = o;
    return;
  }
  __shared__ int cnt[MAXPART];
  int t = threadIdx.x;
  cnt[t] = 0; cnt[t + 512] = 0;
  __syncthreads();
  int eb = (blockIdx.x - cvtBlocks) * EDGES_PER_BLK;
#pragma unroll
  for (int q = 0; q < 8; ++q) {
    int e = eb + q * 512 + t;
    if (e < E) atomicAdd(&cnt[edst[e] >> PSHIFT], 1);
  }
  __syncthreads();
  int c = cnt[t];
  if (c > 0) atomicAdd(&g_hist[t], c);
  c = cnt[t + 512];
  if (c > 0) atomicAdd(&g_hist[t + 512], c);
}

// ---------------------------------------------------------------------------
// Pass B: single-block pair-scan of 1024 partition counts -> part_off
// (exclusive, +end sentinel) and g_cursor (running allocator).
// ---------------------------------------------------------------------------
__global__ __launch_bounds__(512) void part_scan_kernel(
    const int* __restrict__ g_hist, int* __restrict__ part_off,
    int* __restrict__ g_cursor, int E, int npart) {
  __shared__ int ts[512];
  int t = threadIdx.x;
  int i0 = 2 * t, i1 = 2 * t + 1;
  int v0 = (i0 < npart) ? g_hist[i0] : 0;
  int v1 = (i1 < npart) ? g_hist[i1] : 0;
  ts[t] = v0 + v1;
  __syncthreads();
  for (int off = 1; off < 512; off <<= 1) {
    int x = (t >= off) ? ts[t - off] : 0;
    __syncthreads();
    ts[t] += x;
    __syncthreads();
  }
  int excl = ts[t] - (v0 + v1);
  if (i0 < npart) { part_off[i0] = excl; g_cursor[i0] = excl; }
  if (i1 < npart) { part_off[i1] = excl + v0; g_cursor[i1] = excl + v0; }
  if (t == 0) part_off[npart] = E;
}

// ---------------------------------------------------------------------------
// Pass C: LDS-binned scatter.  Per block: 4096 edges -> coeff (bf16),
// counting-sort into LDS by partition, reserve global runs with ONE atomic
// per bin, write coalesced runs of COMPACT records.
// recs4: {src | coeff_bf16<<16} (4B);  dl8: dst&63 (1B).
// ---------------------------------------------------------------------------
__global__ __launch_bounds__(512) void bin_scatter_kernel(
    const float* __restrict__ alpha, const float* __restrict__ ew,
    const int* __restrict__ node_id, const int* __restrict__ esrc,
    const int* __restrict__ edst, int* __restrict__ g_cursor,
    unsigned int* __restrict__ recs4, unsigned char* __restrict__ dl8,
    int E, int gene_num) {
  __shared__ unsigned int lrec[EDGES_PER_BLK];    // 16 KB
  __shared__ unsigned short lbin[EDGES_PER_BLK];  // 8 KB
  __shared__ unsigned char ldl[EDGES_PER_BLK];    // 4 KB
  __shared__ int cnt[MAXPART], offl[MAXPART], gbase[MAXPART];  // 12 KB
  __shared__ int ts[512];

  int t = threadIdx.x;
  cnt[t] = 0; cnt[t + 512] = 0;
  __syncthreads();

  int eb = blockIdx.x * EDGES_PER_BLK;
  unsigned int rx[8]; int rb[8]; int rk[8]; int rdl[8];
#pragma unroll
  for (int q = 0; q < 8; ++q) {
    int e = eb + q * 512 + t;
    rk[q] = -1;
    if (e < E) {
      int src = esrc[e];
      int dst = edst[e];
      int sid = node_id[src];
      int did = node_id[dst];
      int idx;
      if (sid >= 0) idx = (did >= 0) ? gene_num : sid;
      else          idx = (did >= 0) ? did : (gene_num + 1);
      float coeff = alpha[idx] * ew[e];
      rx[q] = (unsigned int)src | ((unsigned int)f2bf(coeff) << 16);
      rdl[q] = dst & (PSIZE - 1);
      int b = dst >> PSHIFT;
      rb[q] = b;
      rk[q] = atomicAdd(&cnt[b], 1);
    }
  }
  __syncthreads();

  // pair-scan of 1024 bins -> offl exclusive
  int c0 = cnt[2 * t], c1 = cnt[2 * t + 1];
  ts[t] = c0 + c1;
  __syncthreads();
  for (int off = 1; off < 512; off <<= 1) {
    int x = (t >= off) ? ts[t - off] : 0;
    __syncthreads();
    ts[t] += x;
    __syncthreads();
  }
  int exclp = ts[t] - (c0 + c1);
  offl[2 * t] = exclp;
  offl[2 * t + 1] = exclp + c0;
  __syncthreads();

  // place into LDS (sorted by partition bin)
#pragma unroll
  for (int q = 0; q < 8; ++q) {
    if (rk[q] >= 0) {
      int ls = offl[rb[q]] + rk[q];
      lrec[ls] = rx[q];
      lbin[ls] = (unsigned short)rb[q];
      ldl[ls] = (unsigned char)rdl[q];
    }
  }
  __syncthreads();

  // reserve global runs (one atomic per nonzero bin)
  {
    int c = cnt[t];
    if (c > 0) gbase[t] = atomicAdd(&g_cursor[t], c);
    c = cnt[t + 512];
    if (c > 0) gbase[t + 512] = atomicAdd(&g_cursor[t + 512], c);
  }
  __syncthreads();

  // coalesced run write-out
  int tot = E - eb;
  if (tot > EDGES_PER_BLK) tot = EDGES_PER_BLK;
  for (int s = t; s < tot; s += 512) {
    int b = lbin[s];
    int pos = gbase[b] + (s - offl[b]);
    recs4[pos] = lrec[s];
    dl8[pos] = ldl[s];
  }
}

// ---------------------------------------------------------------------------
// Pass C2: per-partition sort-once.  Read the partition's compact records,
// counting-sort by dl into PAD-TO-4 LDS slots (pre-zeroed -> pad slots are
// {src 0, coeff 0}), write the padded image to recs4p[p*PSTRIDE] and emit
// cnt_g / pad_g (padded excl offsets) / rk_g (rank->dl, counts descending).
// ---------------------------------------------------------------------------
__global__ __launch_bounds__(512) void sort_kernel(
    const unsigned int* __restrict__ recs4, const unsigned char* __restrict__ dl8,
    const int* __restrict__ part_off, unsigned int* __restrict__ recs4p,
    int* __restrict__ cnt_g, int* __restrict__ pad_g, int* __restrict__ rk_g) {
  __shared__ unsigned int lrec[PSTRIDE];  // 8.75 KB, padded image
  __shared__ int cnt[PSIZE], padl[PSIZE];

  int t = threadIdx.x;
  int p = blockIdx.x;
  if (t < PSIZE) cnt[t] = 0;
  for (int s = t; s < PSTRIDE; s += 512) lrec[s] = 0u;
  __syncthreads();

  int start = part_off[p];
  int R = part_off[p + 1] - start;
  if (R > CAP) R = CAP;

  unsigned int rq[4]; int dlq[4]; int rkq[4];
#pragma unroll
  for (int q = 0; q < 4; ++q) {
    int s = q * 512 + t;
    rkq[q] = -1;
    if (s < R) {
      rq[q] = recs4[start + s];
      int dl = dl8[start + s];
      dlq[q] = dl;
      rkq[q] = atomicAdd(&cnt[dl], 1);
    }
  }
  __syncthreads();

  // exclusive scan of padded (to 4) bin sizes
  if (t < PSIZE) padl[t] = (cnt[t] + 3) & ~3;
  __syncthreads();
  for (int off = 1; off < PSIZE; off <<= 1) {
    int x = 0;
    if (t < PSIZE && t >= off) x = padl[t - off];
    __syncthreads();
    if (t < PSIZE) padl[t] += x;
    __syncthreads();
  }
  if (t < PSIZE) padl[t] -= (cnt[t] + 3) & ~3;
  __syncthreads();

#pragma unroll
  for (int q = 0; q < 4; ++q)
    if (rkq[q] >= 0) lrec[padl[dlq[q]] + rkq[q]] = rq[q];
  __syncthreads();

  int padTot = padl[PSIZE - 1] + ((cnt[PSIZE - 1] + 3) & ~3);
  for (int s = t; s < padTot; s += 512)
    recs4p[(size_t)p * PSTRIDE + s] = lrec[s];
  if (t < PSIZE) {
    cnt_g[p * PSIZE + t] = cnt[t];
    pad_g[p * PSIZE + t] = padl[t];
    // rank of dst t by count descending (ties by index)
    int my = cnt[t];
    int r = 0;
    for (int j = 0; j < PSIZE; ++j) {
      int cj = cnt[j];
      r += (cj > my) || (cj == my && j < t);
    }
    rk_g[p * PSIZE + r] = t;   // rank -> dl
  }
}

// ---------------------------------------------------------------------------
// Pass D: per-(partition, dim-chunk) accumulate.  bid = p*4 + c; round-robin
// block->XCD keeps chunk c on XCDs with xcd&3==c -> 3.2MB h16 slice
// L2-resident.  Block = 256 thr (4 waves x 8 groups of 8 lanes).  Lane owns
// 4 dims (uint2 gather, 64B line per record per group).  Record reads are
// group-uniform uint4 (4 records / DS inst).  Degree-balanced: pass 1 group
// rank = w*8+g, pass 2 rank = 63-(w*8+g) (consecutive ranks in wave = low
// divergence; heavy+light across passes).  8-slot main (8 gathers in
// flight) + 4-slot tail, unguarded (pad slots are real zeros).
// ---------------------------------------------------------------------------
__global__ __launch_bounds__(256) void part_acc_kernel(
    const unsigned short* __restrict__ h16, const unsigned int* __restrict__ recs4p,
    const int* __restrict__ cnt_g, const int* __restrict__ pad_g,
    const int* __restrict__ rk_g, float* __restrict__ neigh, int N) {
  __shared__ __align__(16) unsigned int lrec[PSTRIDE];  // 8.75 KB

  int t = threadIdx.x;
  int p = blockIdx.x >> 2;
  int chunk = blockIdx.x & 3;

  int padTot = pad_g[p * PSIZE + PSIZE - 1] +
               ((cnt_g[p * PSIZE + PSIZE - 1] + 3) & ~3);
  for (int s = t; s < padTot; s += 256)
    lrec[s] = recs4p[(size_t)p * PSTRIDE + s];
  __syncthreads();

  int w = t >> 6;           // wave 0..3
  int l = t & 63;
  int g = l >> 3;           // group in wave 0..7
  int lane8 = l & 7;        // lane in group: 4 dims (2 uints)
  const unsigned int* hpc =
      ((const unsigned int*)h16) + (size_t)chunk * N * 16 + lane8 * 2;

#pragma unroll
  for (int pass = 0; pass < 2; ++pass) {
    int rank = (pass == 0) ? (w * 8 + g) : (63 - (w * 8 + g));
    int myDl = rk_g[p * PSIZE + rank];
    int myCnt = cnt_g[p * PSIZE + myDl];
    int myOff = pad_g[p * PSIZE + myDl];
    int myPad = (myCnt + 3) & ~3;
    float a0 = 0.f, a1 = 0.f, a2 = 0.f, a3 = 0.f;
    int k = 0;
    for (; k + 8 <= myPad; k += 8) {      // 8 gathers in flight per group
      uint4 ra = *(const uint4*)&lrec[myOff + k];
      uint4 rb = *(const uint4*)&lrec[myOff + k + 4];
      uint2 v0 = *(const uint2*)(hpc + (size_t)(ra.x & 0xffffu) * 16);
      uint2 v1 = *(const uint2*)(hpc + (size_t)(ra.y & 0xffffu) * 16);
      uint2 v2 = *(const uint2*)(hpc + (size_t)(ra.z & 0xffffu) * 16);
      uint2 v3 = *(const uint2*)(hpc + (size_t)(ra.w & 0xffffu) * 16);
      uint2 v4 = *(const uint2*)(hpc + (size_t)(rb.x & 0xffffu) * 16);
      uint2 v5 = *(const uint2*)(hpc + (size_t)(rb.y & 0xffffu) * 16);
      uint2 v6 = *(const uint2*)(hpc + (size_t)(rb.z & 0xffffu) * 16);
      uint2 v7 = *(const uint2*)(hpc + (size_t)(rb.w & 0xffffu) * 16);
      float c0 = __uint_as_float(ra.x & 0xffff0000u);
      float c1 = __uint_as_float(ra.y & 0xffff0000u);
      float c2 = __uint_as_float(ra.z & 0xffff0000u);
      float c3 = __uint_as_float(ra.w & 0xffff0000u);
      float c4 = __uint_as_float(rb.x & 0xffff0000u);
      float c5 = __uint_as_float(rb.y & 0xffff0000u);
      float c6 = __uint_as_float(rb.z & 0xffff0000u);
      float c7 = __uint_as_float(rb.w & 0xffff0000u);
      a0 += c0 * __uint_as_float(v0.x << 16);
      a1 += c0 * __uint_as_float(v0.x & 0xffff0000u);
      a2 += c0 * __uint_as_float(v0.y << 16);
      a3 += c0 * __uint_as_float(v0.y & 0xffff0000u);
      a0 += c1 * __uint_as_float(v1.x << 16);
      a1 += c1 * __uint_as_float(v1.x & 0xffff0000u);
      a2 += c1 * __uint_as_float(v1.y << 16);
      a3 += c1 * __uint_as_float(v1.y & 0xffff0000u);
      a0 += c2 * __uint_as_float(v2.x << 16);
      a1 += c2 * __uint_as_float(v2.x & 0xffff0000u);
      a2 += c2 * __uint_as_float(v2.y << 16);
      a3 += c2 * __uint_as_float(v2.y & 0xffff0000u);
      a0 += c3 * __uint_as_float(v3.x << 16);
      a1 += c3 * __uint_as_float(v3.x & 0xffff0000u);
      a2 += c3 * __uint_as_float(v3.y << 16);
      a3 += c3 * __uint_as_float(v3.y & 0xffff0000u);
      a0 += c4 * __uint_as_float(v4.x << 16);
      a1 += c4 * __uint_as_float(v4.x & 0xffff0000u);
      a2 += c4 * __uint_as_float(v4.y << 16);
      a3 += c4 * __uint_as_float(v4.y & 0xffff0000u);
      a0 += c5 * __uint_as_float(v5.x << 16);
      a1 += c5 * __uint_as_float(v5.x & 0xffff0000u);
      a2 += c5 * __uint_as_float(v5.y << 16);
      a3 += c5 * __uint_as_float(v5.y & 0xffff0000u);
      a0 += c6 * __uint_as_float(v6.x << 16);
      a1 += c6 * __uint_as_float(v6.x & 0xffff0000u);
      a2 += c6 * __uint_as_float(v6.y << 16);
      a3 += c6 * __uint_as_float(v6.y & 0xffff0000u);
      a0 += c7 * __uint_as_float(v7.x << 16);
      a1 += c7 * __uint_as_float(v7.x & 0xffff0000u);
      a2 += c7 * __uint_as_float(v7.y << 16);
      a3 += c7 * __uint_as_float(v7.y & 0xffff0000u);
    }
    if (k < myPad) {                       // one 4-slot tail (pads are zero)
      uint4 ra = *(const uint4*)&lrec[myOff + k];
      uint2 v0 = *(const uint2*)(hpc + (size_t)(ra.x & 0xffffu) * 16);
      uint2 v1 = *(const uint2*)(hpc + (size_t)(ra.y & 0xffffu) * 16);
      uint2 v2 = *(const uint2*)(hpc + (size_t)(ra.z & 0xffffu) * 16);
      uint2 v3 = *(const uint2*)(hpc + (size_t)(ra.w & 0xffffu) * 16);
      float c0 = __uint_as_float(ra.x & 0xffff0000u);
      float c1 = __uint_as_float(ra.y & 0xffff0000u);
      float c2 = __uint_as_float(ra.z & 0xffff0000u);
      float c3 = __uint_as_float(ra.w & 0xffff0000u);
      a0 += c0 * __uint_as_float(v0.x << 16);
      a1 += c0 * __uint_as_float(v0.x & 0xffff0000u);
      a2 += c0 * __uint_as_float(v0.y << 16);
      a3 += c0 * __uint_as_float(v0.y & 0xffff0000u);
      a0 += c1 * __uint_as_float(v1.x << 16);
      a1 += c1 * __uint_as_float(v1.x & 0xffff0000u);
      a2 += c1 * __uint_as_float(v1.y << 16);
      a3 += c1 * __uint_as_float(v1.y & 0xffff0000u);
      a0 += c2 * __uint_as_float(v2.x << 16);
      a1 += c2 * __uint_as_float(v2.x & 0xffff0000u);
      a2 += c2 * __uint_as_float(v2.y << 16);
      a3 += c2 * __uint_as_float(v2.y & 0xffff0000u);
      a0 += c3 * __uint_as_float(v3.x << 16);
      a1 += c3 * __uint_as_float(v3.x & 0xffff0000u);
      a2 += c3 * __uint_as_float(v3.y << 16);
      a3 += c3 * __uint_as_float(v3.y & 0xffff0000u);
    }
    int dst = p * PSIZE + myDl;
    if (dst < N) {
      float inv = 1.0f / (float)(myCnt > 0 ? myCnt : 1);
      float4 o = make_float4(a0 * inv, a1 * inv, a2 * inv, a3 * inv);
      ((float4*)neigh)[(size_t)dst * 32 + chunk * 8 + lane8] = o;
    }
  }
}

// ---------------------------------------------------------------------------
// MLP (MFMA): io = relu(io @ W.T + b), in place on d_out.  (unchanged)
// ---------------------------------------------------------------------------
__global__ __launch_bounds__(256) void mlp_mfma_kernel(
    const float* __restrict__ W, const float* __restrict__ bias,
    float* __restrict__ io, int N) {
  __shared__ __align__(16) unsigned short Wl[128 * 128];  // 32 KB bf16

  int t = threadIdx.x;
#pragma unroll
  for (int i = 0; i < 8; ++i) {
    int chunk = t + 256 * i;
    int row = chunk >> 4;
    int cb = chunk & 15;
    const float* gp = W + (size_t)row * 128 + cb * 8;
    float4 a = *(const float4*)gp;
    float4 b = *(const float4*)(gp + 4);
    bf16x8 v;
    v[0] = (short)f2bf(a.x); v[1] = (short)f2bf(a.y);
    v[2] = (short)f2bf(a.z); v[3] = (short)f2bf(a.w);
    v[4] = (short)f2bf(b.x); v[5] = (short)f2bf(b.y);
    v[6] = (short)f2bf(b.z); v[7] = (short)f2bf(b.w);
    *(bf16x8*)((char*)Wl + row * 256 + ((cb ^ (row & 7)) << 4)) = v;
  }
  __syncthreads();

  int l = t & 63;
  int w = t >> 6;
  int kg = l >> 4;
  int m_base = blockIdx.x * 64 + w * 16;
  int arow = m_base + (l & 15);
  if (arow >= N) arow = N - 1;

  bf16x8 af[4];
  const float* ap = io + (size_t)arow * 128 + kg * 8;
#pragma unroll
  for (int kk = 0; kk < 4; ++kk) {
    float4 a = *(const float4*)(ap + kk * 32);
    float4 b = *(const float4*)(ap + kk * 32 + 4);
    bf16x8 v;
    v[0] = (short)f2bf(a.x); v[1] = (short)f2bf(a.y);
    v[2] = (short)f2bf(a.z); v[3] = (short)f2bf(a.w);
    v[4] = (short)f2bf(b.x); v[5] = (short)f2bf(b.y);
    v[6] = (short)f2bf(b.z); v[7] = (short)f2bf(b.w);
    af[kk] = v;
  }

#pragma unroll
  for (int c = 0; c < 8; ++c) {
    f32x4 acc = {0.f, 0.f, 0.f, 0.f};
    int row_w = c * 16 + (l & 15);
    int rs = row_w & 7;
#pragma unroll
    for (int kk = 0; kk < 4; ++kk) {
      int cb = kk * 4 + kg;
      bf16x8 bf = *(bf16x8*)((char*)Wl + row_w * 256 + ((cb ^ rs) << 4));
      acc = __builtin_amdgcn_mfma_f32_16x16x32_bf16(af[kk], bf, acc, 0, 0, 0);
    }
    int j = c * 16 + (l & 15);
    float bj = bias[j];
#pragma unroll
    for (int r = 0; r < 4; ++r) {
      int m = m_base + kg * 4 + r;
      if (m < N) io[(size_t)m * 128 + j] = fmaxf(acc[r] + bj, 0.0f);
    }
  }
}

extern "C" void kernel_launch(void* const* d_in, const int* in_sizes, int n_in,
                              void* d_out, int out_size, void* d_ws, size_t ws_size,
                              hipStream_t stream) {
  const float* h     = (const float*)d_in[0];
  const float* alpha = (const float*)d_in[1];
  const float* ew    = (const float*)d_in[2];
  const float* W     = (const float*)d_in[3];
  const float* bias  = (const float*)d_in[4];
  const int* node_id = (const int*)d_in[5];
  const int* esrc    = (const int*)d_in[6];
  const int* edst    = (const int*)d_in[7];
  float* out = (float*)d_out;

  int E = in_sizes[2];
  int N = in_sizes[5];
  int gene_num = in_sizes[1] - 2;
  int npart = (N + PSIZE - 1) / PSIZE;          // 782 (must be <= 1024)
  int eblocks = (E + EDGES_PER_BLK - 1) / EDGES_PER_BLK;  // 245
  int total4 = N * D / 4;
  int cvtBlocks = (total4 + 511) / 512;         // 3125

  // workspace layout
  int* g_hist   = (int*)d_ws;                   // 1024
  int* part_off = g_hist + MAXPART;             // npart+1 (<=1025)
  int* g_cursor = part_off + MAXPART + 1;       // 1024
  int* cnt_g    = g_cursor + MAXPART;           // npart*64 <= 65536
  int* pad_g    = cnt_g + MAXPART * PSIZE;      // npart*64 <= 65536
  int* rk_g     = pad_g + MAXPART * PSIZE;      // npart*64 <= 65536
  size_t h16_off = ((size_t)(3 * MAXPART + 1 + 3 * MAXPART * PSIZE) * sizeof(int)
                    + 15) & ~(size_t)15;
  unsigned short* h16 = (unsigned short*)((char*)d_ws + h16_off);  // chunk-major
  size_t r4_off = (h16_off + (size_t)N * D * sizeof(unsigned short) + 15) & ~(size_t)15;
  unsigned int* recs4 = (unsigned int*)((char*)d_ws + r4_off);     // (E+8)*4B
  size_t dl_off = (r4_off + (size_t)(E + 8) * 4 + 15) & ~(size_t)15;
  unsigned char* dl8 = (unsigned char*)((char*)d_ws + dl_off);     // E+8
  size_t r4p_off = (dl_off + (size_t)(E + 8) + 15) & ~(size_t)15;
  unsigned int* recs4p = (unsigned int*)((char*)d_ws + r4p_off);   // npart*PSTRIDE*4B
  size_t need = r4p_off + (size_t)npart * PSTRIDE * 4;
  if (ws_size < need) return;

  hipMemsetAsync(g_hist, 0, MAXPART * sizeof(int), stream);

  cvt_hist_kernel<<<cvtBlocks + eblocks, 512, 0, stream>>>(
      h, h16, total4, edst, g_hist, E, cvtBlocks, N);
  part_scan_kernel<<<1, 512, 0, stream>>>(g_hist, part_off, g_cursor, E, npart);
  bin_scatter_kernel<<<eblocks, 512, 0, stream>>>(alpha, ew, node_id, esrc,
                                                  edst, g_cursor, recs4, dl8,
                                                  E, gene_num);
  sort_kernel<<<npart, 512, 0, stream>>>(recs4, dl8, part_off, recs4p,
                                         cnt_g, pad_g, rk_g);
  part_acc_kernel<<<npart * NCHUNK, 256, 0, stream>>>(h16, recs4p, cnt_g,
                                                      pad_g, rk_g, out, N);
  {
    int blocks = (N + 63) / 64;
    mlp_mfma_kernel<<<blocks, 256, 0, stream>>>(W, bias, out, N);
  }
}